// Round 7
// baseline (59.147 us; speedup 1.0000x reference)
//
#include <hip/hip_runtime.h>
#include <math.h>

#define NPTS 4096
#define NBATCH 8

// ws layout (float offsets):
//   [0, 32)      centroid: 4 floats per batch
//   [32, 800)    fused coeffs: A0,A1,A2,vd,vl,beff each [128]
//   [1024, ...)  partial e-triples: float4 per (query, half), idx = (b*4096+n)*2+h
#define WS_CENT 0
#define WS_COEF 32
#define WS_TRI  1024

// blocks 0..7: centroid per batch; block 8: coeff fold.
__launch_bounds__(256)
__global__ void prep_kernel(const float* __restrict__ pts,
                            const float* __restrict__ W_rel, const float* __restrict__ b_rel,
                            const float* __restrict__ W_dist, const float* __restrict__ b_dist,
                            const float* __restrict__ W_dens, const float* __restrict__ b_dens,
                            const float* __restrict__ W_out, const float* __restrict__ b_out,
                            float* __restrict__ ws) {
    __shared__ float sx[256], sy[256], sz[256];
    if (blockIdx.x < NBATCH) {
        int b = blockIdx.x;
        const float* P = pts + (size_t)b * NPTS * 3;
        float ax = 0.f, ay = 0.f, az = 0.f;
        for (int n = threadIdx.x; n < NPTS; n += 256) {
            ax += P[3 * n + 0];
            ay += P[3 * n + 1];
            az += P[3 * n + 2];
        }
        sx[threadIdx.x] = ax; sy[threadIdx.x] = ay; sz[threadIdx.x] = az;
        __syncthreads();
        for (int off = 128; off > 0; off >>= 1) {
            if (threadIdx.x < off) {
                sx[threadIdx.x] += sx[threadIdx.x + off];
                sy[threadIdx.x] += sy[threadIdx.x + off];
                sz[threadIdx.x] += sz[threadIdx.x + off];
            }
            __syncthreads();
        }
        if (threadIdx.x == 0) {
            const float inv = 1.0f / (float)NPTS;
            ws[WS_CENT + 4 * b + 0] = sx[0] * inv;
            ws[WS_CENT + 4 * b + 1] = sy[0] * inv;
            ws[WS_CENT + 4 * b + 2] = sz[0] * inv;
        }
    } else if (threadIdx.x < 128) {
        int o = threadIdx.x;
        float a0 = 0.f, a1 = 0.f, a2 = 0.f, vd = 0.f, vl = 0.f, be = b_out[o];
        for (int j = 0; j < 42; ++j) {
            float w0 = W_out[j * 128 + o];
            float w1 = W_out[(42 + j) * 128 + o];
            float w2 = W_out[(84 + j) * 128 + o];
            a0 = fmaf(W_rel[j],      w0, a0);
            a1 = fmaf(W_rel[42 + j], w0, a1);
            a2 = fmaf(W_rel[84 + j], w0, a2);
            vd = fmaf(W_dist[j],     w1, vd);
            vl = fmaf(W_dens[j],     w2, vl);
            be = fmaf(b_rel[j],  w0, be);
            be = fmaf(b_dist[j], w1, be);
            be = fmaf(b_dens[j], w2, be);
        }
        float* C = ws + WS_COEF;
        C[0 * 128 + o] = a0; C[1 * 128 + o] = a1; C[2 * 128 + o] = a2;
        C[3 * 128 + o] = vd; C[4 * 128 + o] = vl; C[5 * 128 + o] = be;
    }
}

// 3-op sorted-triple insert via med3 (rank-k insert identity). Keeps t0<=t1<=t2.
#define INS3(t0, t1, t2, v)                                   \
    {                                                         \
        float n0 = fminf(t0, (v));                            \
        float n1 = __builtin_amdgcn_fmed3f(t0, t1, (v));      \
        float n2 = __builtin_amdgcn_fmed3f(t1, t2, (v));      \
        t0 = n0; t1 = n1; t2 = n2;                            \
    }

// Merge partner's sorted triple (7 min/max) via xor-butterfly step.
#define MERGE3(t0, t1, t2, m)                                 \
    {                                                         \
        float b0 = __shfl_xor(t0, m);                         \
        float b1 = __shfl_xor(t1, m);                         \
        float b2 = __shfl_xor(t2, m);                         \
        float X = fmaxf(t0, b0);                              \
        t0 = fminf(t0, b0);                                   \
        float Y = fminf(t1, b1);                              \
        float Z = fmaxf(X, Y);                                \
        t1 = fminf(X, Y);                                     \
        t2 = fminf(Z, fminf(t2, b2));                         \
    }

#define RFL(x) __uint_as_float(__builtin_amdgcn_readfirstlane(__float_as_uint(x)))

#define SIG(m) ((m) ^ (((m) >> 3) & 7))

// Query j of this wave: read from GLOBAL pts (query may live in the other
// half). Wave-uniform values forced to SGPRs.
#define DECLQ(j)                                                          \
    float xq##j = QP[3 * (j) + 0];                                        \
    float yq##j = QP[3 * (j) + 1];                                        \
    float zq##j = QP[3 * (j) + 2];                                        \
    float qx##j = RFL(-2.0f * xq##j);                                     \
    float qy##j = RFL(-2.0f * yq##j);                                     \
    float qz##j = RFL(-2.0f * zq##j);                                     \
    float t##j##0 = INFINITY, t##j##1 = INFINITY, t##j##2 = INFINITY;

#define STEP(j)                                                             \
    {                                                                       \
        float e = fmaf(qx##j, c.x, fmaf(qy##j, c.y, fmaf(qz##j, c.z, c.w)));\
        INS3(t##j##0, t##j##1, t##j##2, e);                                 \
    }

// self's e = -|p|^2 is the strict minimum on its lane (only in its own half).
#define SELF(j)                                                             \
    if (selfhalf && lane == ((w << 3) + (j))) {                             \
        t##j##0 = t##j##1; t##j##1 = t##j##2; t##j##2 = INFINITY;           \
    }

#define MRG(j, m) MERGE3(t##j##0, t##j##1, t##j##2, m)

// 1024 blocks x 512 thr (8 waves): block = (batch b, half h, query-group qg of
// 64). Stages 2048 candidates (32 KB, sigma-swizzled) -> 4 blocks/CU = 8
// waves/SIMD (the R3-proven occupancy) while keeping 8 queries/wave economics.
// Writes per-query partial e-triples (e = d^2 - |q|^2, order-equivalent) to ws.
__launch_bounds__(512, 8)
__global__ void scan_kernel(const float* __restrict__ pts, float* __restrict__ ws) {
    __shared__ float4 lp4[2048];   // 32 KB, point m at lp4[SIG(m)]
    int blk = blockIdx.x;
    int b  = blk >> 7;
    int h  = (blk >> 6) & 1;
    int qg = blk & 63;
    int tid = threadIdx.x;
    int w = tid >> 6, lane = tid & 63;

    // stage: thread t -> points 4t..4t+3 of half h (3 coalesced float4 loads)
    {
        const float4* P4 = (const float4*)(pts + ((size_t)b * NPTS + (size_t)h * 2048) * 3);
        float4 v0 = P4[3 * tid + 0];
        float4 v1 = P4[3 * tid + 1];
        float4 v2 = P4[3 * tid + 2];
        int mb = tid << 2;
        #define SQ4(x, y, z) make_float4((x), (y), (z), fmaf((x), (x), fmaf((y), (y), (z) * (z))))
        lp4[SIG(mb + 0)] = SQ4(v0.x, v0.y, v0.z);
        lp4[SIG(mb + 1)] = SQ4(v0.w, v1.x, v1.y);
        lp4[SIG(mb + 2)] = SQ4(v1.z, v1.w, v2.x);
        lp4[SIG(mb + 3)] = SQ4(v2.y, v2.z, v2.w);
        #undef SQ4
    }

    // queries from global (L2-hot), before the barrier to overlap latency
    int nq = (qg << 6) + (w << 3);   // wave's query base within batch
    const float* QP = pts + ((size_t)b * NPTS + nq) * 3;
    DECLQ(0) DECLQ(1) DECLQ(2) DECLQ(3) DECLQ(4) DECLQ(5) DECLQ(6) DECLQ(7)

    __syncthreads();

    // scan 32 tiles of 64 candidates; lane reads candidate (tile*64+lane)
    const float4* cbase = lp4 + SIG(lane);
    #pragma unroll 4
    for (int tile = 0; tile < 32; ++tile) {
        float4 c = cbase[tile << 6];
        STEP(0) STEP(1) STEP(2) STEP(3) STEP(4) STEP(5) STEP(6) STEP(7)
    }

    bool selfhalf = (h == (qg >> 5));
    SELF(0) SELF(1) SELF(2) SELF(3) SELF(4) SELF(5) SELF(6) SELF(7)

    #pragma unroll
    for (int m = 1; m < 64; m <<= 1) {
        MRG(0, m) MRG(1, m) MRG(2, m) MRG(3, m)
        MRG(4, m) MRG(5, m) MRG(6, m) MRG(7, m)
    }

    if (lane == 0) {
        float4* T = (float4*)(ws + WS_TRI) + ((((size_t)b * NPTS + nq) << 1) + h);
        T[0]  = make_float4(t00, t01, t02, 0.f);
        T[2]  = make_float4(t10, t11, t12, 0.f);
        T[4]  = make_float4(t20, t21, t22, 0.f);
        T[6]  = make_float4(t30, t31, t32, 0.f);
        T[8]  = make_float4(t40, t41, t42, 0.f);
        T[10] = make_float4(t50, t51, t52, 0.f);
        T[12] = make_float4(t60, t61, t62, 0.f);
        T[14] = make_float4(t70, t71, t72, 0.f);
    }
}

// 2048 blocks x 256 thr: block = 16 rows; thread -> (row, 8 cols). Merges the
// two half-triples (7 min/max), finishes density, emits fused GEMV row.
__launch_bounds__(256)
__global__ void output_kernel(const float* __restrict__ pts, const float* __restrict__ ws,
                              float* __restrict__ out) {
    int row = blockIdx.x * 16 + (threadIdx.x >> 4);   // global (b*4096+n)
    int b = row >> 12;
    int c16 = threadIdx.x & 15;

    const float4* T = (const float4*)(ws + WS_TRI) + ((size_t)row << 1);
    float4 ta = T[0], tb = T[1];
    float X  = fmaxf(ta.x, tb.x);
    float m0 = fminf(ta.x, tb.x);
    float Y  = fminf(ta.y, tb.y);
    float m1 = fminf(X, Y);
    float Z  = fmaxf(X, Y);
    float m2 = fminf(Z, fminf(ta.z, tb.z));

    const float* P = pts + (size_t)row * 3;
    float px = P[0], py = P[1], pz = P[2];
    float sq = fmaf(px, px, fmaf(py, py, pz * pz));
    float ld = (sqrtf(fmaxf(m0 + sq, 1e-12f)) +
                sqrtf(fmaxf(m1 + sq, 1e-12f)) +
                sqrtf(fmaxf(m2 + sq, 1e-12f))) * (1.0f / 3.0f);

    float cx = ws[WS_CENT + 4 * b + 0];
    float cy = ws[WS_CENT + 4 * b + 1];
    float cz = ws[WS_CENT + 4 * b + 2];
    float rx = px - cx, ry = py - cy, rz = pz - cz;
    float cd = sqrtf(fmaf(rx, rx, fmaf(ry, ry, rz * rz)));

    const float4* Cg = (const float4*)(ws + WS_COEF);  // 6 rows x 32 float4
    float4* orow = (float4*)(out + (size_t)row * 128);
    #pragma unroll
    for (int hh = 0; hh < 2; ++hh) {
        int ob = (c16 << 1) + hh;
        float4 A0 = Cg[0 * 32 + ob];
        float4 A1 = Cg[1 * 32 + ob];
        float4 A2 = Cg[2 * 32 + ob];
        float4 VD = Cg[3 * 32 + ob];
        float4 VL = Cg[4 * 32 + ob];
        float4 BE = Cg[5 * 32 + ob];
        float4 rv;
        rv.x = fmaf(rx, A0.x, fmaf(ry, A1.x, fmaf(rz, A2.x, fmaf(cd, VD.x, fmaf(ld, VL.x, BE.x)))));
        rv.y = fmaf(rx, A0.y, fmaf(ry, A1.y, fmaf(rz, A2.y, fmaf(cd, VD.y, fmaf(ld, VL.y, BE.y)))));
        rv.z = fmaf(rx, A0.z, fmaf(ry, A1.z, fmaf(rz, A2.z, fmaf(cd, VD.z, fmaf(ld, VL.z, BE.z)))));
        rv.w = fmaf(rx, A0.w, fmaf(ry, A1.w, fmaf(rz, A2.w, fmaf(cd, VD.w, fmaf(ld, VL.w, BE.w)))));
        orow[ob] = rv;
    }
}

extern "C" void kernel_launch(void* const* d_in, const int* in_sizes, int n_in,
                              void* d_out, int out_size, void* d_ws, size_t ws_size,
                              hipStream_t stream) {
    const float* pts    = (const float*)d_in[0];
    const float* W_rel  = (const float*)d_in[1];
    const float* b_rel  = (const float*)d_in[2];
    const float* W_dist = (const float*)d_in[3];
    const float* b_dist = (const float*)d_in[4];
    const float* W_dens = (const float*)d_in[5];
    const float* b_dens = (const float*)d_in[6];
    const float* W_out  = (const float*)d_in[7];
    const float* b_out  = (const float*)d_in[8];
    float* out = (float*)d_out;
    float* ws  = (float*)d_ws;

    hipLaunchKernelGGL(prep_kernel, dim3(NBATCH + 1), dim3(256), 0, stream,
                       pts, W_rel, b_rel, W_dist, b_dist, W_dens, b_dens, W_out, b_out, ws);
    hipLaunchKernelGGL(scan_kernel, dim3(1024), dim3(512), 0, stream, pts, ws);
    hipLaunchKernelGGL(output_kernel, dim3(2048), dim3(256), 0, stream, pts, ws, out);
}

// Round 8
// 45.852 us; speedup vs baseline: 1.2900x; 1.2900x over previous
//
#include <hip/hip_runtime.h>
#include <math.h>

#define NPTS 4096
#define NBATCH 8

// ws layout (float offsets):
//   [0, 32)      centroid: 4 floats per batch
//   [32, 800)    fused coeffs: A0,A1,A2,vd,vl,beff each [128]
//   [1024, ...)  partial e-triples: float4 per (query, half), idx = (b*4096+n)*2+h
#define WS_CENT 0
#define WS_COEF 32
#define WS_TRI  1024

// blocks 0..7: centroid per batch; block 8: coeff fold.
__launch_bounds__(256)
__global__ void prep_kernel(const float* __restrict__ pts,
                            const float* __restrict__ W_rel, const float* __restrict__ b_rel,
                            const float* __restrict__ W_dist, const float* __restrict__ b_dist,
                            const float* __restrict__ W_dens, const float* __restrict__ b_dens,
                            const float* __restrict__ W_out, const float* __restrict__ b_out,
                            float* __restrict__ ws) {
    __shared__ float sx[256], sy[256], sz[256];
    if (blockIdx.x < NBATCH) {
        int b = blockIdx.x;
        const float* P = pts + (size_t)b * NPTS * 3;
        float ax = 0.f, ay = 0.f, az = 0.f;
        for (int n = threadIdx.x; n < NPTS; n += 256) {
            ax += P[3 * n + 0];
            ay += P[3 * n + 1];
            az += P[3 * n + 2];
        }
        sx[threadIdx.x] = ax; sy[threadIdx.x] = ay; sz[threadIdx.x] = az;
        __syncthreads();
        for (int off = 128; off > 0; off >>= 1) {
            if (threadIdx.x < off) {
                sx[threadIdx.x] += sx[threadIdx.x + off];
                sy[threadIdx.x] += sy[threadIdx.x + off];
                sz[threadIdx.x] += sz[threadIdx.x + off];
            }
            __syncthreads();
        }
        if (threadIdx.x == 0) {
            const float inv = 1.0f / (float)NPTS;
            ws[WS_CENT + 4 * b + 0] = sx[0] * inv;
            ws[WS_CENT + 4 * b + 1] = sy[0] * inv;
            ws[WS_CENT + 4 * b + 2] = sz[0] * inv;
        }
    } else if (threadIdx.x < 128) {
        int o = threadIdx.x;
        float a0 = 0.f, a1 = 0.f, a2 = 0.f, vd = 0.f, vl = 0.f, be = b_out[o];
        for (int j = 0; j < 42; ++j) {
            float w0 = W_out[j * 128 + o];
            float w1 = W_out[(42 + j) * 128 + o];
            float w2 = W_out[(84 + j) * 128 + o];
            a0 = fmaf(W_rel[j],      w0, a0);
            a1 = fmaf(W_rel[42 + j], w0, a1);
            a2 = fmaf(W_rel[84 + j], w0, a2);
            vd = fmaf(W_dist[j],     w1, vd);
            vl = fmaf(W_dens[j],     w2, vl);
            be = fmaf(b_rel[j],  w0, be);
            be = fmaf(b_dist[j], w1, be);
            be = fmaf(b_dens[j], w2, be);
        }
        float* C = ws + WS_COEF;
        C[0 * 128 + o] = a0; C[1 * 128 + o] = a1; C[2 * 128 + o] = a2;
        C[3 * 128 + o] = vd; C[4 * 128 + o] = vl; C[5 * 128 + o] = be;
    }
}

// 3-op sorted-triple insert via med3 (rank-k insert identity). Keeps t0<=t1<=t2.
#define INS3(t0, t1, t2, v)                                   \
    {                                                         \
        float n0 = fminf(t0, (v));                            \
        float n1 = __builtin_amdgcn_fmed3f(t0, t1, (v));      \
        float n2 = __builtin_amdgcn_fmed3f(t1, t2, (v));      \
        t0 = n0; t1 = n1; t2 = n2;                            \
    }

// Merge partner's sorted triple (7 min/max) via xor-butterfly step.
#define MERGE3(t0, t1, t2, m)                                 \
    {                                                         \
        float b0 = __shfl_xor(t0, m);                         \
        float b1 = __shfl_xor(t1, m);                         \
        float b2 = __shfl_xor(t2, m);                         \
        float X = fmaxf(t0, b0);                              \
        t0 = fminf(t0, b0);                                   \
        float Y = fminf(t1, b1);                              \
        float Z = fmaxf(X, Y);                                \
        t1 = fminf(X, Y);                                     \
        t2 = fminf(Z, fminf(t2, b2));                         \
    }

#define RFL(x) __uint_as_float(__builtin_amdgcn_readfirstlane(__float_as_uint(x)))

#define SIG(m) ((m) ^ (((m) >> 3) & 7))

// Query j of this wave: read from GLOBAL pts (query may live in the other
// half). Wave-uniform values forced to SGPRs.
#define DECLQ(j)                                                          \
    float xq##j = QP[3 * (j) + 0];                                        \
    float yq##j = QP[3 * (j) + 1];                                        \
    float zq##j = QP[3 * (j) + 2];                                        \
    float qx##j = RFL(-2.0f * xq##j);                                     \
    float qy##j = RFL(-2.0f * yq##j);                                     \
    float qz##j = RFL(-2.0f * zq##j);                                     \
    float t##j##0 = INFINITY, t##j##1 = INFINITY, t##j##2 = INFINITY;

#define STEP(j)                                                             \
    {                                                                       \
        float e = fmaf(qx##j, c.x, fmaf(qy##j, c.y, fmaf(qz##j, c.z, c.w)));\
        INS3(t##j##0, t##j##1, t##j##2, e);                                 \
    }

// self's e = -|p|^2 is the strict minimum on its lane (only in its own half).
#define SELF(j)                                                             \
    if (selfhalf && lane == ((w << 3) + (j))) {                             \
        t##j##0 = t##j##1; t##j##1 = t##j##2; t##j##2 = INFINITY;           \
    }

#define MRG(j, m) MERGE3(t##j##0, t##j##1, t##j##2, m)

// 1024 blocks x 512 thr (8 waves): block = (batch b, half h, query-group qg of
// 64). Stages 2048 candidates (32 KB, sigma-swizzled). launch_bounds(512,4)
// only CAPS VGPR at 128; natural allocation ~56 (R6-measured) -> no spills,
// and runtime occupancy = min(LDS: 5 blocks, wave cap: 4 blocks) = 4 blocks/CU
// = 8 waves/SIMD (the R3-proven occupancy) with 8-query/wave economics.
__launch_bounds__(512, 4)
__global__ void scan_kernel(const float* __restrict__ pts, float* __restrict__ ws) {
    __shared__ float4 lp4[2048];   // 32 KB, point m at lp4[SIG(m)]
    int blk = blockIdx.x;
    int b  = blk >> 7;
    int h  = (blk >> 6) & 1;
    int qg = blk & 63;
    int tid = threadIdx.x;
    int w = tid >> 6, lane = tid & 63;

    // stage: thread t -> points 4t..4t+3 of half h (3 coalesced float4 loads)
    {
        const float4* P4 = (const float4*)(pts + ((size_t)b * NPTS + (size_t)h * 2048) * 3);
        float4 v0 = P4[3 * tid + 0];
        float4 v1 = P4[3 * tid + 1];
        float4 v2 = P4[3 * tid + 2];
        int mb = tid << 2;
        #define SQ4(x, y, z) make_float4((x), (y), (z), fmaf((x), (x), fmaf((y), (y), (z) * (z))))
        lp4[SIG(mb + 0)] = SQ4(v0.x, v0.y, v0.z);
        lp4[SIG(mb + 1)] = SQ4(v0.w, v1.x, v1.y);
        lp4[SIG(mb + 2)] = SQ4(v1.z, v1.w, v2.x);
        lp4[SIG(mb + 3)] = SQ4(v2.y, v2.z, v2.w);
        #undef SQ4
    }

    // queries from global (L2-hot), before the barrier to overlap latency
    int nq = (qg << 6) + (w << 3);   // wave's query base within batch
    const float* QP = pts + ((size_t)b * NPTS + nq) * 3;
    DECLQ(0) DECLQ(1) DECLQ(2) DECLQ(3) DECLQ(4) DECLQ(5) DECLQ(6) DECLQ(7)

    __syncthreads();

    // scan 32 tiles of 64 candidates; lane reads candidate (tile*64+lane)
    const float4* cbase = lp4 + SIG(lane);
    #pragma unroll 4
    for (int tile = 0; tile < 32; ++tile) {
        float4 c = cbase[tile << 6];
        STEP(0) STEP(1) STEP(2) STEP(3) STEP(4) STEP(5) STEP(6) STEP(7)
    }

    bool selfhalf = (h == (qg >> 5));
    SELF(0) SELF(1) SELF(2) SELF(3) SELF(4) SELF(5) SELF(6) SELF(7)

    #pragma unroll
    for (int m = 1; m < 64; m <<= 1) {
        MRG(0, m) MRG(1, m) MRG(2, m) MRG(3, m)
        MRG(4, m) MRG(5, m) MRG(6, m) MRG(7, m)
    }

    if (lane == 0) {
        float4* T = (float4*)(ws + WS_TRI) + ((((size_t)b * NPTS + nq) << 1) + h);
        T[0]  = make_float4(t00, t01, t02, 0.f);
        T[2]  = make_float4(t10, t11, t12, 0.f);
        T[4]  = make_float4(t20, t21, t22, 0.f);
        T[6]  = make_float4(t30, t31, t32, 0.f);
        T[8]  = make_float4(t40, t41, t42, 0.f);
        T[10] = make_float4(t50, t51, t52, 0.f);
        T[12] = make_float4(t60, t61, t62, 0.f);
        T[14] = make_float4(t70, t71, t72, 0.f);
    }
}

// 2048 blocks x 256 thr: block = 16 rows; thread -> (row, 8 cols). Merges the
// two half-triples (7 min/max), finishes density, emits fused GEMV row.
__launch_bounds__(256)
__global__ void output_kernel(const float* __restrict__ pts, const float* __restrict__ ws,
                              float* __restrict__ out) {
    int row = blockIdx.x * 16 + (threadIdx.x >> 4);   // global (b*4096+n)
    int b = row >> 12;
    int c16 = threadIdx.x & 15;

    const float4* T = (const float4*)(ws + WS_TRI) + ((size_t)row << 1);
    float4 ta = T[0], tb = T[1];
    float X  = fmaxf(ta.x, tb.x);
    float m0 = fminf(ta.x, tb.x);
    float Y  = fminf(ta.y, tb.y);
    float m1 = fminf(X, Y);
    float Z  = fmaxf(X, Y);
    float m2 = fminf(Z, fminf(ta.z, tb.z));

    const float* P = pts + (size_t)row * 3;
    float px = P[0], py = P[1], pz = P[2];
    float sq = fmaf(px, px, fmaf(py, py, pz * pz));
    float ld = (sqrtf(fmaxf(m0 + sq, 1e-12f)) +
                sqrtf(fmaxf(m1 + sq, 1e-12f)) +
                sqrtf(fmaxf(m2 + sq, 1e-12f))) * (1.0f / 3.0f);

    float cx = ws[WS_CENT + 4 * b + 0];
    float cy = ws[WS_CENT + 4 * b + 1];
    float cz = ws[WS_CENT + 4 * b + 2];
    float rx = px - cx, ry = py - cy, rz = pz - cz;
    float cd = sqrtf(fmaf(rx, rx, fmaf(ry, ry, rz * rz)));

    const float4* Cg = (const float4*)(ws + WS_COEF);  // 6 rows x 32 float4
    float4* orow = (float4*)(out + (size_t)row * 128);
    #pragma unroll
    for (int hh = 0; hh < 2; ++hh) {
        int ob = (c16 << 1) + hh;
        float4 A0 = Cg[0 * 32 + ob];
        float4 A1 = Cg[1 * 32 + ob];
        float4 A2 = Cg[2 * 32 + ob];
        float4 VD = Cg[3 * 32 + ob];
        float4 VL = Cg[4 * 32 + ob];
        float4 BE = Cg[5 * 32 + ob];
        float4 rv;
        rv.x = fmaf(rx, A0.x, fmaf(ry, A1.x, fmaf(rz, A2.x, fmaf(cd, VD.x, fmaf(ld, VL.x, BE.x)))));
        rv.y = fmaf(rx, A0.y, fmaf(ry, A1.y, fmaf(rz, A2.y, fmaf(cd, VD.y, fmaf(ld, VL.y, BE.y)))));
        rv.z = fmaf(rx, A0.z, fmaf(ry, A1.z, fmaf(rz, A2.z, fmaf(cd, VD.z, fmaf(ld, VL.z, BE.z)))));
        rv.w = fmaf(rx, A0.w, fmaf(ry, A1.w, fmaf(rz, A2.w, fmaf(cd, VD.w, fmaf(ld, VL.w, BE.w)))));
        orow[ob] = rv;
    }
}

extern "C" void kernel_launch(void* const* d_in, const int* in_sizes, int n_in,
                              void* d_out, int out_size, void* d_ws, size_t ws_size,
                              hipStream_t stream) {
    const float* pts    = (const float*)d_in[0];
    const float* W_rel  = (const float*)d_in[1];
    const float* b_rel  = (const float*)d_in[2];
    const float* W_dist = (const float*)d_in[3];
    const float* b_dist = (const float*)d_in[4];
    const float* W_dens = (const float*)d_in[5];
    const float* b_dens = (const float*)d_in[6];
    const float* W_out  = (const float*)d_in[7];
    const float* b_out  = (const float*)d_in[8];
    float* out = (float*)d_out;
    float* ws  = (float*)d_ws;

    hipLaunchKernelGGL(prep_kernel, dim3(NBATCH + 1), dim3(256), 0, stream,
                       pts, W_rel, b_rel, W_dist, b_dist, W_dens, b_dens, W_out, b_out, ws);
    hipLaunchKernelGGL(scan_kernel, dim3(1024), dim3(512), 0, stream, pts, ws);
    hipLaunchKernelGGL(output_kernel, dim3(2048), dim3(256), 0, stream, pts, ws, out);
}